// Round 4
// baseline (118.141 us; speedup 1.0000x reference)
//
#include <hip/hip_runtime.h>
#include <limits.h>
#include <stdint.h>

#define ALPHA 0.2f
#define HALFA 0.1f
static constexpr int N = 8192;
static constexpr int D = 128;
static constexpr int C = 512;
static constexpr int BT = 128;                    // term2 tile edge / term1 point count
static constexpr int GR = D / 8;                  // 16 granules (half8) per row
static constexpr int SL = BT + 1;                 // padded row count per granule
static constexpr int MAXG = 64;                   // e-list capacity
static constexpr int NB = N / BT;                 // 64
static constexpr int NTRI = NB * (NB + 1) / 2;    // 2080 term2 triangle tiles
static constexpr int T1 = (C / 64) * (N / BT);    // 8*64 = 512 term1 half-tiles (64c x 128j)
static constexpr int NTILES = T1 + NTRI;          // 2592
static constexpr int GRID = 512;                  // persistent blocks, ~5 tiles each

using half8    = __attribute__((ext_vector_type(8))) _Float16;
using floatx16 = __attribute__((ext_vector_type(16))) float;

__device__ __forceinline__ floatx16 zerov() { floatx16 v = {0.f}; return v; }

__device__ __forceinline__ half8 cvt8(float4 v0, float4 v1) {
    half8 h;
    h[0] = (_Float16)v0.x; h[1] = (_Float16)v0.y; h[2] = (_Float16)v0.z; h[3] = (_Float16)v0.w;
    h[4] = (_Float16)v1.x; h[5] = (_Float16)v1.y; h[6] = (_Float16)v1.z; h[7] = (_Float16)v1.w;
    return h;
}

__device__ __forceinline__ float ss8(float4 v0, float4 v1) {
    return v0.x*v0.x + v0.y*v0.y + v0.z*v0.z + v0.w*v0.w
         + v1.x*v1.x + v1.y*v1.y + v1.z*v1.z + v1.w*v1.w;
}

// ---- k_prep: anchors + xh (fp16) + sq + ap (proven, ~4 us) ----------------------------

__launch_bounds__(256)
__global__ void k_prep(const float* __restrict__ x, const int* __restrict__ labels,
                       _Float16* __restrict__ xh, float* __restrict__ sq,
                       int* __restrict__ anchorg, float* __restrict__ ap,
                       float* __restrict__ out) {
    __shared__ int sAnc[C];
    const int tid = threadIdx.x;
    if (blockIdx.x == 0 && tid == 0) out[0] = 0.f;
    for (int i = tid; i < C; i += 256) sAnc[i] = INT_MAX;
    __syncthreads();
    const int4* lab4 = (const int4*)labels;
    for (int t = tid; t < N / 4; t += 256) {
        int4 lv = lab4[t];
        int base = 4 * t;
        atomicMin(&sAnc[lv.x], base);
        atomicMin(&sAnc[lv.y], base + 1);
        atomicMin(&sAnc[lv.z], base + 2);
        atomicMin(&sAnc[lv.w], base + 3);
    }
    __syncthreads();
    if (tid < 2) {
        int c = blockIdx.x * 2 + tid;
        int a = sAnc[c];
        anchorg[c] = (a == INT_MAX) ? -1 : a;
    }

    const int r = blockIdx.x * 32 + (tid >> 3);
    const int sub = tid & 7;
    const float4* src = (const float4*)(x + (size_t)r * D) + sub * 4;
    half8* dst = (half8*)(xh + (size_t)r * D) + sub * 2;
    half8 hj[2];
    float ssj = 0.f;
#pragma unroll
    for (int i = 0; i < 2; ++i) {
        float4 v0 = src[2 * i], v1 = src[2 * i + 1];
        hj[i] = cvt8(v0, v1);
        dst[i] = hj[i];
        ssj += ss8(v0, v1);
    }
    ssj += __shfl_xor(ssj, 1); ssj += __shfl_xor(ssj, 2); ssj += __shfl_xor(ssj, 4);

    const int a = sAnc[labels[r]];
    const float4* asrc = (const float4*)(x + (size_t)a * D) + sub * 4;
    float ssa = 0.f, dot = 0.f;
#pragma unroll
    for (int i = 0; i < 2; ++i) {
        float4 a0 = asrc[2 * i], a1 = asrc[2 * i + 1];
        half8 ha = cvt8(a0, a1);
        ssa += ss8(a0, a1);
#pragma unroll
        for (int e = 0; e < 8; ++e) dot = fmaf((float)ha[e], (float)hj[i][e], dot);
    }
    ssa += __shfl_xor(ssa, 1); ssa += __shfl_xor(ssa, 2); ssa += __shfl_xor(ssa, 4);
    dot += __shfl_xor(dot, 1); dot += __shfl_xor(dot, 2); dot += __shfl_xor(dot, 4);
    if (sub == 0) {
        sq[r] = ssj;
        ap[r] = ssa + ssj - 2.f * dot;
    }
}

// ---- k_main: persistent blocks, static tile schedule, cross-tile prefetch -------------
// Slot s for block b: s = b + k*GRID. s < T1 -> term1 half-tile (every block's FIRST tile),
// else term2 triangle tile s-T1. A-fragments live in registers; next tile's A loads issue
// right after the last MFMA (same regs, WAR-safe) and hide under the epilogue.

__device__ __forceinline__ void dec_tri(int t, int& br, int& bc) {
    int rem = t, b = 0;
    while (rem >= NB - b) { rem -= NB - b; ++b; }
    br = b; bc = b + rem;
}

__launch_bounds__(512, 4)
__global__ void k_main(const _Float16* __restrict__ xh, const int* __restrict__ labels,
                       const int* __restrict__ anchor, const float* __restrict__ sq,
                       const float* __restrict__ ap, float* __restrict__ out) {
    __shared__ __align__(16) _Float16 BsH[GR * SL * 8];   // 33024 B, K-major [granule][row]
    __shared__ __align__(16) float sge[64 * MAXG];        // 16 KB e-lists (term1)
    __shared__ float4 rowE[BT];
    __shared__ float4 colE[BT];
    __shared__ int   sArow[64];
    __shared__ float sSqA[64];
    __shared__ int   sCnt[64];
    __shared__ float wsum[8];
    half8* Bs = (half8*)BsH;

    const int tid = threadIdx.x;
    const int lane = tid & 63, w = tid >> 6;
    const int m = lane & 31, q = lane >> 5;
    const int wr = w >> 1, wc = w & 1;        // term2: 4 row-groups x 2 col-groups
    const int wr2 = w >> 2, wc4 = w & 3;      // term1: 2 row-groups x 4 col-groups
    const int sg = tid & 15, sr0 = tid >> 4;  // staging: granule, row base
    float local = 0.f;

    half8 af[8];      // A fragments (current tile); reused as prefetch target
    half8 breg[4];    // B staging registers (next tile)

    for (int s = blockIdx.x; s < NTILES; s += GRID) {
        // next-tile coords (always a term2 tile when it exists)
        int i0n = 0, j0n = 0;
        const bool hasNext = (s + GRID < NTILES);
        if (hasNext) {
            int brn, bcn; dec_tri(s + GRID - T1, brn, bcn);
            i0n = brn * BT; j0n = bcn * BT;
        }

        if (s < T1) {
            // ---------------- term1 half-tile: 64 anchors x 128 points ----------------
            const int cb = s >> 6, jb = s & 63;
            const int c0 = cb * 64, j0 = jb * BT;

            if (tid < 64) {
                int a = anchor[c0 + tid];
                int ar = (a < 0) ? 0 : a;             // dummy (absent class never matches)
                sArow[tid] = ar; sSqA[tid] = sq[ar]; sCnt[tid] = 0;
            } else if (tid < 192) {
                int j = j0 + tid - 64;
                colE[tid - 64] = make_float4(sq[j], __int_as_float(labels[j]), 0.f, 0.f);
            }
            {   // pre-fill e-lists with +inf-ish so the hinge loop runs unmasked in 4s
                float4 big = make_float4(1e30f, 1e30f, 1e30f, 1e30f);
                ((float4*)sge)[tid * 2] = big; ((float4*)sge)[tid * 2 + 1] = big;
            }
            __syncthreads();

            // A gather (registers) + B stage + label scan, all overlapped
            {
                int arow = sArow[wr2 * 32 + m];
                const half8* aptr = (const half8*)(xh + (size_t)arow * D) + q;
#pragma unroll
                for (int k = 0; k < 8; ++k) af[k] = aptr[2 * k];
            }
#pragma unroll
            for (int i = 0; i < 4; ++i) {
                int row = sr0 + 32 * i;
                Bs[sg * SL + row] = *((const half8*)(xh + (size_t)(j0 + row) * D) + sg);
            }
            {
                const int4* lab4 = (const int4*)labels;
                for (int t = tid; t < N / 4; t += 512) {
                    int4 lv = lab4[t];
                    int base = 4 * t;
#pragma unroll
                    for (int kk = 0; kk < 4; ++kk) {
                        int l = (kk == 0) ? lv.x : (kk == 1) ? lv.y : (kk == 2) ? lv.z : lv.w;
                        int li = l - c0;
                        if ((unsigned)li < 64u) {
                            int idx = base + kk;
                            if (idx != sArow[li]) {
                                int slot = atomicAdd(&sCnt[li], 1);
                                if (slot < MAXG) sge[li * MAXG + slot] = ap[idx] + HALFA;
                            }
                        }
                    }
                }
            }
            __syncthreads();

            floatx16 acc = zerov();
#pragma unroll
            for (int k = 0; k < 8; ++k) {
                half8 b0 = Bs[(2 * k + q) * SL + wc4 * 32 + m];
                acc = __builtin_amdgcn_mfma_f32_32x32x16_f16(af[k], b0, acc, 0, 0, 0);
            }
            // prefetch next tile's A into af (dead after MFMA); hides under hinge epilogue
            if (hasNext) {
                const half8* aptr = (const half8*)(xh + (size_t)(i0n + wr * 32 + m) * D) + q;
#pragma unroll
                for (int k = 0; k < 8; ++k) af[k] = aptr[2 * k];
            }
            // hinge epilogue
            {
                float4 cj = colE[wc4 * 32 + m];
                float sqj = cj.x; int labj = __float_as_int(cj.y);
#pragma unroll
                for (int rr = 0; rr < 16; ++rr) {
                    int row = wr2 * 32 + (rr & 3) + 8 * (rr >> 2) + 4 * q;
                    float Dv = fmaf(-2.f, acc[rr], sSqA[row] + sqj);
                    bool vld = (labj != c0 + row);
                    int n = sCnt[row]; n = (n > MAXG) ? MAXG : n;
                    int nf = (n + 3) & ~3;
                    for (int gb = 0; gb < nf; gb += 4) {
                        float4 ev = *(const float4*)&sge[row * MAXG + gb];
                        float u;
                        u = ev.x - Dv; if (vld && __builtin_fabsf(u) < HALFA) local += u + HALFA;
                        u = ev.y - Dv; if (vld && __builtin_fabsf(u) < HALFA) local += u + HALFA;
                        u = ev.z - Dv; if (vld && __builtin_fabsf(u) < HALFA) local += u + HALFA;
                        u = ev.w - Dv; if (vld && __builtin_fabsf(u) < HALFA) local += u + HALFA;
                    }
                }
            }
            // prefetch next tile's B into regs; ds_write happens at next loop head
            if (hasNext) {
#pragma unroll
                for (int i = 0; i < 4; ++i)
                    breg[i] = *((const half8*)(xh + (size_t)(j0n + sr0 + 32 * i) * D) + sg);
            }
            __syncthreads();
        } else {
            // ---------------- term2: symmetric Gram triangle tile, 128x128 ----------------
            int br, bc; dec_tri(s - T1, br, bc);
            const int i0 = br * BT, j0 = bc * BT;
            const bool diag = (br == bc);

            if (tid < BT) {
                int i = i0 + tid;
                int li = labels[i]; int a = anchor[li];
                float sqi = sq[i];
                float e2 = (i == a) ? -1e30f : ap[i] + HALFA - sqi;
                rowE[tid] = make_float4(e2, __int_as_float(li), sqi, 0.f);
            } else if (tid < 2 * BT) {
                int t = tid - BT;
                int j = j0 + t;
                int lj = labels[j]; int a = anchor[lj];
                float sqj = sq[j];
                float e2 = (j == a) ? -1e30f : ap[j] + HALFA - sqj;
                colE[t] = make_float4(e2, __int_as_float(lj), sqj, 0.f);
            }
            // write prefetched B into LDS (af/breg were loaded during previous tile)
#pragma unroll
            for (int i = 0; i < 4; ++i)
                Bs[sg * SL + sr0 + 32 * i] = breg[i];
            __syncthreads();

            floatx16 acc0 = zerov(), acc1 = zerov();
#pragma unroll
            for (int k = 0; k < 8; ++k) {
                half8 b0 = Bs[(2 * k + q) * SL + wc * 64 + m];
                half8 b1 = Bs[(2 * k + q) * SL + wc * 64 + 32 + m];
                acc0 = __builtin_amdgcn_mfma_f32_32x32x16_f16(af[k], b0, acc0, 0, 0, 0);
                acc1 = __builtin_amdgcn_mfma_f32_32x32x16_f16(af[k], b1, acc1, 0, 0, 0);
            }
            // prefetch next A (af dead after MFMA); hides under epilogue
            if (hasNext) {
                const half8* aptr = (const half8*)(xh + (size_t)(i0n + wr * 32 + m) * D) + q;
#pragma unroll
                for (int k = 0; k < 8; ++k) af[k] = aptr[2 * k];
            }

            float sqjv[2], e2j[2]; int labj[2];
            { float4 cj = colE[wc * 64 + m];      e2j[0] = cj.x; labj[0] = __float_as_int(cj.y); sqjv[0] = cj.z; }
            { float4 cj = colE[wc * 64 + 32 + m]; e2j[1] = cj.x; labj[1] = __float_as_int(cj.y); sqjv[1] = cj.z; }

#pragma unroll
            for (int rr = 0; rr < 16; ++rr) {
                int row = wr * 32 + (rr & 3) + 8 * (rr >> 2) + 4 * q;
                float4 re = rowE[row];
                float e2i = re.x, sqi = re.z;
                int labi = __float_as_int(re.y);
                {
                    float dot = acc0[rr];
                    if (labi != labj[0]) {
                        float u2 = fmaf(2.f, dot, e2i - sqjv[0]);
                        if (__builtin_fabsf(u2) < HALFA) local += u2 + HALFA;
                        if (!diag) {
                            float u2b = fmaf(2.f, dot, e2j[0] - sqi);
                            if (__builtin_fabsf(u2b) < HALFA) local += u2b + HALFA;
                        }
                    }
                }
                {
                    float dot = acc1[rr];
                    if (labi != labj[1]) {
                        float u2 = fmaf(2.f, dot, e2i - sqjv[1]);
                        if (__builtin_fabsf(u2) < HALFA) local += u2 + HALFA;
                        if (!diag) {
                            float u2b = fmaf(2.f, dot, e2j[1] - sqi);
                            if (__builtin_fabsf(u2b) < HALFA) local += u2b + HALFA;
                        }
                    }
                }
            }
            // prefetch next B into regs
            if (hasNext) {
#pragma unroll
                for (int i = 0; i < 4; ++i)
                    breg[i] = *((const half8*)(xh + (size_t)(j0n + sr0 + 32 * i) * D) + sg);
            }
            __syncthreads();
        }
    }

    // block reduce -> one atomic (once per persistent block)
#pragma unroll
    for (int off = 32; off; off >>= 1) local += __shfl_down(local, off);
    if (lane == 0) wsum[w] = local;
    __syncthreads();
    if (tid == 0) {
        float ssum = 0.f;
#pragma unroll
        for (int i = 0; i < 8; ++i) ssum += wsum[i];
        atomicAdd(out, ssum);
    }
}

// ---------------- launch ----------------

extern "C" void kernel_launch(void* const* d_in, const int* in_sizes, int n_in,
                              void* d_out, int out_size, void* d_ws, size_t ws_size,
                              hipStream_t stream) {
    const float* x = (const float*)d_in[0];
    const int* labels = (const int*)d_in[1];
    float* out = (float*)d_out;

    char* p = (char*)d_ws;
    int* anchor = (int*)p;        p += C * 4;
    float* sq = (float*)p;        p += N * 4;
    float* ap = (float*)p;        p += N * 4;
    p = (char*)(((uintptr_t)p + 255) & ~(uintptr_t)255);
    _Float16* xh = (_Float16*)p;  // N*D*2 = 2 MB

    k_prep<<<N / 32, 256, 0, stream>>>(x, labels, xh, sq, anchor, ap, out);
    k_main<<<GRID, 512, 0, stream>>>(xh, labels, anchor, sq, ap, out);
}

// Round 5
// 113.355 us; speedup vs baseline: 1.0422x; 1.0422x over previous
//
#include <hip/hip_runtime.h>
#include <limits.h>
#include <stdint.h>

#define ALPHA 0.2f
#define HALFA 0.1f
static constexpr int N = 8192;
static constexpr int D = 128;
static constexpr int C = 512;
static constexpr int BT = 128;                    // tile edge (points per tile)
static constexpr int GR = D / 8;                  // 16 granules (half8) per row
static constexpr int SL = BT + 1;                 // padded row count per granule
static constexpr int MAXG = 64;                   // e-list capacity
static constexpr int NB = N / BT;                 // 64 row/col panels
static constexpr int NT1 = (C / 64) * (N / BT);   // 512 term1 half-tiles (64c x 128j)
static constexpr int NSP = NB / 2;                // 32 superpanels (panel k + panel 63-k)
static constexpr int SPB = 16;                    // blocks per superpanel
static constexpr int GRID = NT1 + NSP * SPB;      // 1024 blocks

using half8    = __attribute__((ext_vector_type(8))) _Float16;
using floatx16 = __attribute__((ext_vector_type(16))) float;

__device__ __forceinline__ floatx16 zerov() { floatx16 v = {0.f}; return v; }

__device__ __forceinline__ half8 cvt8(float4 v0, float4 v1) {
    half8 h;
    h[0] = (_Float16)v0.x; h[1] = (_Float16)v0.y; h[2] = (_Float16)v0.z; h[3] = (_Float16)v0.w;
    h[4] = (_Float16)v1.x; h[5] = (_Float16)v1.y; h[6] = (_Float16)v1.z; h[7] = (_Float16)v1.w;
    return h;
}

__device__ __forceinline__ float ss8(float4 v0, float4 v1) {
    return v0.x*v0.x + v0.y*v0.y + v0.z*v0.z + v0.w*v0.w
         + v1.x*v1.x + v1.y*v1.y + v1.z*v1.z + v1.w*v1.w;
}

// superpanel k: tiles 0..lenA-1 are (br=k, bc=k+t); rest are (br=63-k, bc=63-k+t-lenA)
__device__ __forceinline__ void dec_sp(int k, int t, int lenA, int& br, int& bc) {
    if (t < lenA) { br = k;      bc = k + t; }
    else          { br = 63 - k; bc = 63 - k + (t - lenA); }
}

// ---- k_prep: anchors + xh (fp16) + sq + ap (proven, ~5 us) ----------------------------

__launch_bounds__(256)
__global__ void k_prep(const float* __restrict__ x, const int* __restrict__ labels,
                       _Float16* __restrict__ xh, float* __restrict__ sq,
                       int* __restrict__ anchorg, float* __restrict__ ap,
                       float* __restrict__ out) {
    __shared__ int sAnc[C];
    const int tid = threadIdx.x;
    if (blockIdx.x == 0 && tid == 0) out[0] = 0.f;
    for (int i = tid; i < C; i += 256) sAnc[i] = INT_MAX;
    __syncthreads();
    const int4* lab4 = (const int4*)labels;
    for (int t = tid; t < N / 4; t += 256) {
        int4 lv = lab4[t];
        int base = 4 * t;
        atomicMin(&sAnc[lv.x], base);
        atomicMin(&sAnc[lv.y], base + 1);
        atomicMin(&sAnc[lv.z], base + 2);
        atomicMin(&sAnc[lv.w], base + 3);
    }
    __syncthreads();
    if (tid < 2) {
        int c = blockIdx.x * 2 + tid;
        int a = sAnc[c];
        anchorg[c] = (a == INT_MAX) ? -1 : a;
    }

    const int r = blockIdx.x * 32 + (tid >> 3);
    const int sub = tid & 7;
    const float4* src = (const float4*)(x + (size_t)r * D) + sub * 4;
    half8* dst = (half8*)(xh + (size_t)r * D) + sub * 2;
    half8 hj[2];
    float ssj = 0.f;
#pragma unroll
    for (int i = 0; i < 2; ++i) {
        float4 v0 = src[2 * i], v1 = src[2 * i + 1];
        hj[i] = cvt8(v0, v1);
        dst[i] = hj[i];
        ssj += ss8(v0, v1);
    }
    ssj += __shfl_xor(ssj, 1); ssj += __shfl_xor(ssj, 2); ssj += __shfl_xor(ssj, 4);

    const int a = sAnc[labels[r]];
    const float4* asrc = (const float4*)(x + (size_t)a * D) + sub * 4;
    float ssa = 0.f, dot = 0.f;
#pragma unroll
    for (int i = 0; i < 2; ++i) {
        float4 a0 = asrc[2 * i], a1 = asrc[2 * i + 1];
        half8 ha = cvt8(a0, a1);
        ssa += ss8(a0, a1);
#pragma unroll
        for (int e = 0; e < 8; ++e) dot = fmaf((float)ha[e], (float)hj[i][e], dot);
    }
    ssa += __shfl_xor(ssa, 1); ssa += __shfl_xor(ssa, 2); ssa += __shfl_xor(ssa, 4);
    dot += __shfl_xor(dot, 1); dot += __shfl_xor(dot, 2); dot += __shfl_xor(dot, 4);
    if (sub == 0) {
        sq[r] = ssj;
        ap[r] = ssa + ssj - 2.f * dot;
    }
}

// ---- k_main -----------------------------------------------------------------------------
// Blocks 0..NT1-1: term1 half-tiles (64 anchors x 128 points), one per block.
// Blocks NT1..: term2 superpanel walkers: fixed-A panel, ~4 tiles each, B+colE prefetched
// across tiles (issue-early / consume-late), af reloaded only at the panel seam.

__launch_bounds__(512, 2)
__global__ void k_main(const _Float16* __restrict__ xh, const int* __restrict__ labels,
                       const int* __restrict__ anchor, const float* __restrict__ sq,
                       const float* __restrict__ ap, float* __restrict__ out) {
    __shared__ __align__(16) _Float16 BsH[GR * SL * 8];   // 33024 B, K-major [granule][row]
    __shared__ __align__(16) float sge[64 * MAXG];        // 16 KB e-lists (term1)
    __shared__ float4 rowE[BT];
    __shared__ float4 colE[2][BT];
    __shared__ int   sArow[64];
    __shared__ float sSqA[64];
    __shared__ int   sCnt[64];
    __shared__ float wsum[8];
    half8* Bs = (half8*)BsH;

    const int tid = threadIdx.x;
    const int lane = tid & 63, w = tid >> 6;
    const int m = lane & 31, q = lane >> 5;
    const int sg = tid & 15, sr0 = tid >> 4;   // staging: granule, row base
    float local = 0.f;

    if ((int)blockIdx.x < NT1) {
        // ---------------- term1 half-tile: 64 anchors x 128 points ----------------
        const int cb = blockIdx.x >> 6, jb = blockIdx.x & 63;
        const int c0 = cb * 64, j0 = jb * BT;
        const int wr2 = w >> 2, wc4 = w & 3;   // 2 row-groups x 4 col-groups

        if (tid < 64) {
            int a = anchor[c0 + tid];
            int ar = (a < 0) ? 0 : a;          // dummy (absent class never contributes)
            sArow[tid] = ar; sSqA[tid] = sq[ar]; sCnt[tid] = 0;
        } else if (tid < 192) {
            int j = j0 + tid - 64;
            colE[0][tid - 64] = make_float4(sq[j], __int_as_float(labels[j]), 0.f, 0.f);
        }
        {   // pre-fill e-lists so the hinge loop runs unmasked in float4s
            float4 big = make_float4(1e30f, 1e30f, 1e30f, 1e30f);
            ((float4*)sge)[tid * 2] = big; ((float4*)sge)[tid * 2 + 1] = big;
        }
        __syncthreads();

        // A gather (registers) + B stage + label scan, overlapped
        half8 af[8];
        {
            int arow = sArow[wr2 * 32 + m];
            const half8* aptr = (const half8*)(xh + (size_t)arow * D) + q;
#pragma unroll
            for (int k = 0; k < 8; ++k) af[k] = aptr[2 * k];
        }
#pragma unroll
        for (int i = 0; i < 4; ++i) {
            int row = sr0 + 32 * i;
            Bs[sg * SL + row] = *((const half8*)(xh + (size_t)(j0 + row) * D) + sg);
        }
        {
            const int4* lab4 = (const int4*)labels;
            for (int t = tid; t < N / 4; t += 512) {
                int4 lv = lab4[t];
                int base = 4 * t;
#pragma unroll
                for (int kk = 0; kk < 4; ++kk) {
                    int l = (kk == 0) ? lv.x : (kk == 1) ? lv.y : (kk == 2) ? lv.z : lv.w;
                    int li = l - c0;
                    if ((unsigned)li < 64u) {
                        int idx = base + kk;
                        if (idx != sArow[li]) {
                            int slot = atomicAdd(&sCnt[li], 1);
                            if (slot < MAXG) sge[li * MAXG + slot] = ap[idx] + HALFA;
                        }
                    }
                }
            }
        }
        __syncthreads();

        floatx16 acc = zerov();
#pragma unroll
        for (int k = 0; k < 8; ++k) {
            half8 b0 = Bs[(2 * k + q) * SL + wc4 * 32 + m];
            acc = __builtin_amdgcn_mfma_f32_32x32x16_f16(af[k], b0, acc, 0, 0, 0);
        }

        float4 cj = colE[0][wc4 * 32 + m];
        float sqj = cj.x; int labj = __float_as_int(cj.y);
#pragma unroll
        for (int rr = 0; rr < 16; ++rr) {
            int row = wr2 * 32 + (rr & 3) + 8 * (rr >> 2) + 4 * q;
            float Dv = fmaf(-2.f, acc[rr], sSqA[row] + sqj);
            bool vld = (labj != c0 + row);
            int n = sCnt[row]; n = (n > MAXG) ? MAXG : n;
            int nf = (n + 3) & ~3;
            for (int gb = 0; gb < nf; gb += 4) {
                float4 ev = *(const float4*)&sge[row * MAXG + gb];
                float u;
                u = ev.x - Dv; if (vld && __builtin_fabsf(u) < HALFA) local += u + HALFA;
                u = ev.y - Dv; if (vld && __builtin_fabsf(u) < HALFA) local += u + HALFA;
                u = ev.z - Dv; if (vld && __builtin_fabsf(u) < HALFA) local += u + HALFA;
                u = ev.w - Dv; if (vld && __builtin_fabsf(u) < HALFA) local += u + HALFA;
            }
        }
    } else {
        // ---------------- term2: superpanel walker ----------------
        const int bi = blockIdx.x - NT1;
        const int k = bi >> 4, p = bi & 15;
        const int lenA = 64 - k;
        const int wr = w >> 1, wc = w & 1;     // 4 row-groups x 2 col-groups
        int cbuf = 0, cur_br = -1;
        half8 af[8], breg[4];

        // prologue: prefetch first tile's B and colE[0]
        {
            int br0, bc0; dec_sp(k, p, lenA, br0, bc0);
            int j0 = bc0 * BT;
#pragma unroll
            for (int i = 0; i < 4; ++i)
                breg[i] = *((const half8*)(xh + (size_t)(j0 + sr0 + 32 * i) * D) + sg);
            if (tid < BT) {
                int j = j0 + tid;
                int lj = labels[j]; int a = anchor[lj];
                float sqj = sq[j];
                float e2 = (j == a) ? -1e30f : ap[j] + HALFA - sqj;
                colE[0][tid] = make_float4(e2, __int_as_float(lj), sqj, 0.f);
            }
        }

        for (int t = p; t < 65; t += SPB) {
            int br, bc; dec_sp(k, t, lenA, br, bc);
            const int i0 = br * BT, j0n_unused = bc;
            (void)j0n_unused;
            const bool diag = (br == bc);

            if (br != cur_br) {
                cur_br = br;
                const half8* aptr = (const half8*)(xh + (size_t)(i0 + wr * 32 + m) * D) + q;
#pragma unroll
                for (int kk = 0; kk < 8; ++kk) af[kk] = aptr[2 * kk];
                if (tid < BT) {
                    int i = i0 + tid;
                    int li = labels[i]; int a = anchor[li];
                    float sqi = sq[i];
                    float e2 = (i == a) ? -1e30f : ap[i] + HALFA - sqi;
                    rowE[tid] = make_float4(e2, __int_as_float(li), sqi, 0.f);
                }
            }

            // commit prefetched B into LDS (waits its vmcnt automatically)
#pragma unroll
            for (int i = 0; i < 4; ++i)
                Bs[sg * SL + sr0 + 32 * i] = breg[i];
            __syncthreads();

            // prefetch next tile (consumed after the next barrier pair)
            if (t + SPB < 65) {
                int brn, bcn; dec_sp(k, t + SPB, lenA, brn, bcn);
                int j0n = bcn * BT;
#pragma unroll
                for (int i = 0; i < 4; ++i)
                    breg[i] = *((const half8*)(xh + (size_t)(j0n + sr0 + 32 * i) * D) + sg);
                if (tid < BT) {
                    int j = j0n + tid;
                    int lj = labels[j]; int a = anchor[lj];
                    float sqj = sq[j];
                    float e2 = (j == a) ? -1e30f : ap[j] + HALFA - sqj;
                    colE[cbuf ^ 1][tid] = make_float4(e2, __int_as_float(lj), sqj, 0.f);
                }
            }

            floatx16 acc0 = zerov(), acc1 = zerov();
#pragma unroll
            for (int kk = 0; kk < 8; ++kk) {
                half8 b0 = Bs[(2 * kk + q) * SL + wc * 64 + m];
                half8 b1 = Bs[(2 * kk + q) * SL + wc * 64 + 32 + m];
                acc0 = __builtin_amdgcn_mfma_f32_32x32x16_f16(af[kk], b0, acc0, 0, 0, 0);
                acc1 = __builtin_amdgcn_mfma_f32_32x32x16_f16(af[kk], b1, acc1, 0, 0, 0);
            }

            float sqjv[2], e2j[2]; int labj[2];
            { float4 cj = colE[cbuf][wc * 64 + m];      e2j[0] = cj.x; labj[0] = __float_as_int(cj.y); sqjv[0] = cj.z; }
            { float4 cj = colE[cbuf][wc * 64 + 32 + m]; e2j[1] = cj.x; labj[1] = __float_as_int(cj.y); sqjv[1] = cj.z; }

#pragma unroll
            for (int rr = 0; rr < 16; ++rr) {
                int row = wr * 32 + (rr & 3) + 8 * (rr >> 2) + 4 * q;
                float4 re = rowE[row];
                float e2i = re.x, sqi = re.z;
                int labi = __float_as_int(re.y);
                {
                    float dot = acc0[rr];
                    if (labi != labj[0]) {
                        float u2 = fmaf(2.f, dot, e2i - sqjv[0]);
                        if (__builtin_fabsf(u2) < HALFA) local += u2 + HALFA;
                        if (!diag) {
                            float u2b = fmaf(2.f, dot, e2j[0] - sqi);
                            if (__builtin_fabsf(u2b) < HALFA) local += u2b + HALFA;
                        }
                    }
                }
                {
                    float dot = acc1[rr];
                    if (labi != labj[1]) {
                        float u2 = fmaf(2.f, dot, e2i - sqjv[1]);
                        if (__builtin_fabsf(u2) < HALFA) local += u2 + HALFA;
                        if (!diag) {
                            float u2b = fmaf(2.f, dot, e2j[1] - sqi);
                            if (__builtin_fabsf(u2b) < HALFA) local += u2b + HALFA;
                        }
                    }
                }
            }
            cbuf ^= 1;
            __syncthreads();   // protect Bs (rewritten next iter) and colE[cbuf^1]
        }
    }

    // block reduce -> one atomic
#pragma unroll
    for (int off = 32; off; off >>= 1) local += __shfl_down(local, off);
    if (lane == 0) wsum[w] = local;
    __syncthreads();
    if (tid == 0) {
        float s = 0.f;
#pragma unroll
        for (int i = 0; i < 8; ++i) s += wsum[i];
        atomicAdd(out, s);
    }
}

// ---------------- launch ----------------

extern "C" void kernel_launch(void* const* d_in, const int* in_sizes, int n_in,
                              void* d_out, int out_size, void* d_ws, size_t ws_size,
                              hipStream_t stream) {
    const float* x = (const float*)d_in[0];
    const int* labels = (const int*)d_in[1];
    float* out = (float*)d_out;

    char* p = (char*)d_ws;
    int* anchor = (int*)p;        p += C * 4;
    float* sq = (float*)p;        p += N * 4;
    float* ap = (float*)p;        p += N * 4;
    p = (char*)(((uintptr_t)p + 255) & ~(uintptr_t)255);
    _Float16* xh = (_Float16*)p;  // N*D*2 = 2 MB

    k_prep<<<N / 32, 256, 0, stream>>>(x, labels, xh, sq, anchor, ap, out);
    k_main<<<GRID, 512, 0, stream>>>(xh, labels, anchor, sq, ap, out);
}